// Round 1
// baseline (1062.395 us; speedup 1.0000x reference)
//
#include <hip/hip_runtime.h>
#include <math.h>

#define NB 8
#define NC 64
#define NH 256
#define NW 256
#define NHW 65536
#define NM 32
#define NPS 4194304   // C*H*W per sample
#define GN_EPS 1e-5f
#define OMEGA 0.0245436926061703f  // 2*pi/256

__device__ __forceinline__ float gelu_f(float v) {
    return 0.5f * v * (1.0f + erff(v * 0.7071067811865475f));
}

// ---------------- K0: zero GN accumulators, compute FiLM gamma/beta per (b,c)
__global__ void k0_init(const float* __restrict__ t_in,
                        const float* __restrict__ gamma_w, const float* __restrict__ gamma_b,
                        const float* __restrict__ beta_w, const float* __restrict__ beta_b,
                        float* __restrict__ gn_acc, float* __restrict__ gamma_bc,
                        float* __restrict__ beta_bc) {
    int t = threadIdx.x;
    if (t < 32) gn_acc[t] = 0.f;
    for (int idx = t; idx < NB * NC; idx += 256) {
        int b = idx >> 6, o = idx & 63;
        float g = gamma_b[o], be = beta_b[o];
        for (int c = 0; c < NC; ++c) {
            float tv = t_in[b * NC + c];
            g += gamma_w[o * NC + c] * tv;
            be += beta_w[o * NC + c] * tv;
        }
        gamma_bc[idx] = g;
        beta_bc[idx] = be;
    }
}

// ---------------- K1: real DFT along W, keep kx 0..31.  Xw[bc][h][kx]
__global__ __launch_bounds__(128) void k1_dftw(const float* __restrict__ x,
                                               float* __restrict__ xw_re,
                                               float* __restrict__ xw_im) {
    __shared__ float xs[32 * 257];
    int blk = blockIdx.x;        // 4096 = 512 bc * 8 hchunks
    int bc = blk >> 3;
    int h0 = (blk & 7) * 32;
    const float* src = x + (size_t)bc * NHW + (size_t)h0 * NW;
    for (int idx = threadIdx.x; idx < 2048; idx += 128) {
        float4 v = ((const float4*)src)[idx];
        int r = idx >> 6;
        int w = (idx & 63) * 4;
        float* d = &xs[r * 257 + w];
        d[0] = v.x; d[1] = v.y; d[2] = v.z; d[3] = v.w;
    }
    __syncthreads();
    int t = threadIdx.x;
    int row = t >> 2;       // 0..31
    int kgrp = t & 3;       // kx = kgrp*8 + j
    float cd[8], sd[8], cc[8], ss[8], ar[8], ai[8];
#pragma unroll
    for (int j = 0; j < 8; ++j) {
        int kx = kgrp * 8 + j;
        sincosf(OMEGA * (float)kx, &sd[j], &cd[j]);
        cc[j] = 1.f; ss[j] = 0.f; ar[j] = 0.f; ai[j] = 0.f;
    }
    const float* xrow = &xs[row * 257];
    for (int w = 0; w < 256; ++w) {
        float xv = xrow[w];
#pragma unroll
        for (int j = 0; j < 8; ++j) {
            ar[j] += xv * cc[j];        // e^{-i th}: re += x cos
            ai[j] -= xv * ss[j];        // im -= x sin
            float c2 = cc[j] * cd[j] - ss[j] * sd[j];
            ss[j] = ss[j] * cd[j] + cc[j] * sd[j];
            cc[j] = c2;
        }
    }
    size_t rowg = (size_t)bc * NH + h0 + row;
#pragma unroll
    for (int j = 0; j < 8; ++j) {
        int kx = kgrp * 8 + j;
        xw_re[rowg * NM + kx] = ar[j];
        xw_im[rowg * NM + kx] = ai[j];
    }
}

// ---------------- K2: complex DFT along H at kept rows.  Xf[bc][j64][kx]
__global__ __launch_bounds__(256) void k2_dfth(const float* __restrict__ xw_re,
                                               const float* __restrict__ xw_im,
                                               float* __restrict__ xf_re,
                                               float* __restrict__ xf_im) {
    __shared__ float xr_l[NH * NM];
    __shared__ float xi_l[NH * NM];
    int bc = blockIdx.x;
    size_t base = (size_t)bc * NH * NM;
    for (int idx = threadIdx.x; idx < NH * NM / 4; idx += 256) {
        ((float4*)xr_l)[idx] = ((const float4*)(xw_re + base))[idx];
        ((float4*)xi_l)[idx] = ((const float4*)(xw_im + base))[idx];
    }
    __syncthreads();
    int t = threadIdx.x;
    int kx = t & 31, jgrp = t >> 5;
    float cd[8], sd[8], cc[8], ss[8], ar[8], ai[8];
#pragma unroll
    for (int jj = 0; jj < 8; ++jj) {
        int j = jgrp * 8 + jj;
        int f = (j < 32) ? j : 192 + j;     // actual row frequency
        sincosf(OMEGA * (float)f, &sd[jj], &cd[jj]);
        cc[jj] = 1.f; ss[jj] = 0.f; ar[jj] = 0.f; ai[jj] = 0.f;
    }
    for (int h = 0; h < 256; ++h) {
        float xr = xr_l[h * NM + kx], xi = xi_l[h * NM + kx];
#pragma unroll
        for (int jj = 0; jj < 8; ++jj) {
            // (xr + i xi) * (c - i s)
            ar[jj] += xr * cc[jj] + xi * ss[jj];
            ai[jj] += xi * cc[jj] - xr * ss[jj];
            float c2 = cc[jj] * cd[jj] - ss[jj] * sd[jj];
            ss[jj] = ss[jj] * cd[jj] + cc[jj] * sd[jj];
            cc[jj] = c2;
        }
    }
    size_t ob = (size_t)bc * 2048;
#pragma unroll
    for (int jj = 0; jj < 8; ++jj) {
        int j = jgrp * 8 + jj;
        xf_re[ob + j * 32 + kx] = ar[jj];
        xf_im[ob + j * 32 + kx] = ai[jj];
    }
}

// ---------------- K3: per-mode complex channel mix.  Yf[b][o][ky][kx]
__global__ __launch_bounds__(256) void k3_mix(const float* __restrict__ xf_re,
                                              const float* __restrict__ xf_im,
                                              const float* __restrict__ w1r, const float* __restrict__ w1i,
                                              const float* __restrict__ w2r, const float* __restrict__ w2i,
                                              float* __restrict__ yf_re, float* __restrict__ yf_im) {
    __shared__ float xr_l[4 * 64 * 32];
    __shared__ float xi_l[4 * 64 * 32];
    int blk = blockIdx.x;          // ((ky*8 + oct)*2 + bh)
    int bh = blk & 1;
    int oct = (blk >> 1) & 7;
    int ky = blk >> 4;
    for (int idx = threadIdx.x; idx < 4 * 64 * 32; idx += 256) {
        int bb = idx >> 11;
        int i = (idx >> 5) & 63;
        int kx = idx & 31;
        size_t g = ((size_t)((bh * 4 + bb) * 64 + i) * 64 + ky) * 32 + kx;
        xr_l[idx] = xf_re[g];
        xi_l[idx] = xf_im[g];
    }
    __syncthreads();
    const float* wr = (ky < 32) ? w1r : w2r;
    const float* wi = (ky < 32) ? w1i : w2i;
    int kyl = ky & 31;
    int t = threadIdx.x;
    int kx = t & 31, oo = t >> 5;
    int o = oct * 8 + oo;
    float accr[4] = {0.f, 0.f, 0.f, 0.f};
    float acci[4] = {0.f, 0.f, 0.f, 0.f};
    for (int i = 0; i < 64; ++i) {
        size_t wbase = ((size_t)(i * 64 + o) * 32 + kyl) * 32 + kx;
        float wrv = wr[wbase];
        float wiv = wi[wbase];
#pragma unroll
        for (int bb = 0; bb < 4; ++bb) {
            float xr = xr_l[(bb * 64 + i) * 32 + kx];
            float xi = xi_l[(bb * 64 + i) * 32 + kx];
            accr[bb] += xr * wrv - xi * wiv;
            acci[bb] += xr * wiv + xi * wrv;
        }
    }
#pragma unroll
    for (int bb = 0; bb < 4; ++bb) {
        int b = bh * 4 + bb;
        size_t g = ((size_t)(b * 64 + o) * 64 + ky) * 32 + kx;
        yf_re[g] = accr[bb];
        yf_im[g] = acci[bb];
    }
}

// ---------------- K4: inverse DFT along H (only 64 nonzero rows).  Yh[bc][h][kx]
__global__ __launch_bounds__(256) void k4_idfth(const float* __restrict__ yf_re,
                                                const float* __restrict__ yf_im,
                                                float* __restrict__ yh_re,
                                                float* __restrict__ yh_im) {
    __shared__ float yr_l[2048];
    __shared__ float yi_l[2048];
    int blk = blockIdx.x;
    int bc = blk >> 2, hq = blk & 3;
    size_t base = (size_t)bc * 2048;
    for (int idx = threadIdx.x; idx < 512; idx += 256) {
        ((float4*)yr_l)[idx] = ((const float4*)(yf_re + base))[idx];
        ((float4*)yi_l)[idx] = ((const float4*)(yf_im + base))[idx];
    }
    __syncthreads();
    int t = threadIdx.x;
    int kx = t & 31, hgrp = t >> 5;
    int h0 = hq * 64 + hgrp * 8;
    float cdh[8], sdh[8], cc[8], ss[8], ar[8], ai[8];
#pragma unroll
    for (int hh = 0; hh < 8; ++hh) {
        sincosf(OMEGA * (float)(h0 + hh), &sdh[hh], &cdh[hh]);
        cc[hh] = 1.f; ss[hh] = 0.f; ar[hh] = 0.f; ai[hh] = 0.f;
    }
    for (int j = 0; j < 64; ++j) {
        if (j == 32) {
            // state is e^{+i*32*w*h}; needed row freq 224 == -32 -> conjugate
#pragma unroll
            for (int hh = 0; hh < 8; ++hh) ss[hh] = -ss[hh];
        }
        float yr = yr_l[j * 32 + kx], yi = yi_l[j * 32 + kx];
#pragma unroll
        for (int hh = 0; hh < 8; ++hh) {
            // (yr + i yi) * (c + i s)
            ar[hh] += yr * cc[hh] - yi * ss[hh];
            ai[hh] += yr * ss[hh] + yi * cc[hh];
            float c2 = cc[hh] * cdh[hh] - ss[hh] * sdh[hh];
            ss[hh] = ss[hh] * cdh[hh] + cc[hh] * sdh[hh];
            cc[hh] = c2;
        }
    }
    const float sc = 1.0f / 65536.0f;   // 1/(H*W) folded here
#pragma unroll
    for (int hh = 0; hh < 8; ++hh) {
        size_t g = ((size_t)bc * NH + h0 + hh) * NM + kx;
        yh_re[g] = ar[hh] * sc;
        yh_im[g] = ai[hh] * sc;
    }
}

// ---------------- K5: inverse real DFT along W + GN1 statistics.  y -> d_out
__global__ __launch_bounds__(128) void k5_irfftw(const float* __restrict__ yh_re,
                                                 const float* __restrict__ yh_im,
                                                 float* __restrict__ yout,
                                                 float* __restrict__ gn_acc) {
    __shared__ float zr_l[128 * 33];
    __shared__ float zi_l[128 * 33];
    __shared__ float rsum[2], rsq[2];
    int blk = blockIdx.x;
    int bc = blk >> 1, hhalf = blk & 1;
    size_t base = ((size_t)bc * NH + hhalf * 128) * NM;
    for (int idx = threadIdx.x; idx < 128 * 32; idx += 128) {
        int hl = idx >> 5, kx = idx & 31;
        zr_l[hl * 33 + kx] = yh_re[base + idx];
        zi_l[hl * 33 + kx] = yh_im[base + idx];
    }
    __syncthreads();
    int t = threadIdx.x;
    float zr[32], zi[32];
#pragma unroll
    for (int kx = 0; kx < 32; ++kx) {
        float m = (kx == 0) ? 1.f : 2.f;   // irfft doubling for kx>=1
        zr[kx] = zr_l[t * 33 + kx] * m;
        zi[kx] = zi_l[t * 33 + kx] * m;
    }
    int h = hhalf * 128 + t;
    float* orow = yout + (size_t)bc * NHW + (size_t)h * NW;
    float cw = 1.f, sw = 0.f;
    float cdw, sdw;
    sincosf(OMEGA, &sdw, &cdw);
    float sum = 0.f, sq = 0.f;
    for (int w4 = 0; w4 < 64; ++w4) {
        float res[4];
#pragma unroll
        for (int q = 0; q < 4; ++q) {
            float c = cw, s = sw;          // e^{+i*w*kx}, kx = 1
            float acc = zr[0];             // DC: Re only (pocketfft semantics)
#pragma unroll
            for (int kx = 1; kx < 32; ++kx) {
                acc += zr[kx] * c - zi[kx] * s;
                float c2 = c * cw - s * sw;
                s = s * cw + c * sw;
                c = c2;
            }
            res[q] = acc;
            sum += acc;
            sq += acc * acc;
            float c2 = cw * cdw - sw * sdw;  // advance w
            sw = sw * cdw + cw * sdw;
            cw = c2;
        }
        ((float4*)orow)[w4] = make_float4(res[0], res[1], res[2], res[3]);
    }
#pragma unroll
    for (int off = 32; off > 0; off >>= 1) {
        sum += __shfl_down(sum, off);
        sq += __shfl_down(sq, off);
    }
    int lane = t & 63, wv = t >> 6;
    if (lane == 0) { rsum[wv] = sum; rsq[wv] = sq; }
    __syncthreads();
    if (t == 0) {
        int b = bc >> 6;
        atomicAdd(&gn_acc[b * 4 + 0], rsum[0] + rsum[1]);
        atomicAdd(&gn_acc[b * 4 + 1], rsq[0] + rsq[1]);
    }
}

// ---------------- K6: GN1 + residual + gelu + MLP (64->32->64) + GN2 stats
__global__ __launch_bounds__(256) void k6_mlp(const float* __restrict__ x,
                                              const float* __restrict__ norm1_w,
                                              const float* __restrict__ norm1_b,
                                              const float* __restrict__ mlp_w1,
                                              const float* __restrict__ mlp_b1,
                                              const float* __restrict__ mlp_w2,
                                              const float* __restrict__ mlp_b2,
                                              float* __restrict__ y,
                                              float* __restrict__ gn_acc) {
    __shared__ float w1l[2048], w2l[2048], b1l[32], b2l[64], nwl[64], nbl[64];
    __shared__ float rsum[4], rsq[4];
    int t = threadIdx.x;
    for (int idx = t; idx < 2048; idx += 256) {
        w1l[idx] = mlp_w1[idx];
        w2l[idx] = mlp_w2[idx];
    }
    if (t < 32) b1l[t] = mlp_b1[t];
    if (t < 64) { b2l[t] = mlp_b2[t]; nwl[t] = norm1_w[t]; nbl[t] = norm1_b[t]; }
    __syncthreads();
    int blk = blockIdx.x;
    int b = blk >> 8;
    int pix = (blk & 255) * 256 + t;
    const float invN = 1.0f / (float)NPS;
    float m1 = gn_acc[b * 4 + 0] * invN;
    float var1 = gn_acc[b * 4 + 1] * invN - m1 * m1;
    float rs1 = rsqrtf(var1 + GN_EPS);
    size_t base = (size_t)b * NC * NHW + pix;
    float v[64];
#pragma unroll
    for (int c = 0; c < 64; ++c) {
        float yv = y[base + (size_t)c * NHW];
        float xv = x[base + (size_t)c * NHW];
        float g = (yv - m1) * rs1 * nwl[c] + nbl[c] + xv;
        v[c] = gelu_f(g);
    }
    float hv[32];
#pragma unroll
    for (int j = 0; j < 32; ++j) {
        float a = b1l[j];
#pragma unroll
        for (int c = 0; c < 64; ++c) a += w1l[j * 64 + c] * v[c];
        hv[j] = gelu_f(a);
    }
    float sum = 0.f, sq = 0.f;
#pragma unroll
    for (int c = 0; c < 64; ++c) {
        float a = b2l[c];
#pragma unroll
        for (int j = 0; j < 32; ++j) a += w2l[c * 32 + j] * hv[j];
        y[base + (size_t)c * NHW] = a;
        sum += a;
        sq += a * a;
    }
#pragma unroll
    for (int off = 32; off > 0; off >>= 1) {
        sum += __shfl_down(sum, off);
        sq += __shfl_down(sq, off);
    }
    int lane = t & 63, wv = t >> 6;
    if (lane == 0) { rsum[wv] = sum; rsq[wv] = sq; }
    __syncthreads();
    if (t == 0) {
        atomicAdd(&gn_acc[b * 4 + 2], rsum[0] + rsum[1] + rsum[2] + rsum[3]);
        atomicAdd(&gn_acc[b * 4 + 3], rsq[0] + rsq[1] + rsq[2] + rsq[3]);
    }
}

// ---------------- K7: GN2 + FiLM + gelu(x) skip, elementwise, in-place
__global__ __launch_bounds__(256) void k7_final(const float* __restrict__ x,
                                                const float* __restrict__ gamma_bc,
                                                const float* __restrict__ beta_bc,
                                                const float* __restrict__ gn_acc,
                                                float* __restrict__ y) {
    size_t idx4 = (size_t)blockIdx.x * 256 + threadIdx.x;
    size_t base = idx4 * 4;
    int b = (int)(base >> 22);
    int c = (int)((base >> 16) & 63);
    const float invN = 1.0f / (float)NPS;
    float m2 = gn_acc[b * 4 + 2] * invN;
    float var2 = gn_acc[b * 4 + 3] * invN - m2 * m2;
    float rs2 = rsqrtf(var2 + GN_EPS);
    float g = gamma_bc[b * 64 + c];
    float be = beta_bc[b * 64 + c];
    float4 yv = ((float4*)y)[idx4];
    float4 xv = ((const float4*)x)[idx4];
    yv.x = g * ((yv.x - m2) * rs2) + be + gelu_f(xv.x);
    yv.y = g * ((yv.y - m2) * rs2) + be + gelu_f(xv.y);
    yv.z = g * ((yv.z - m2) * rs2) + be + gelu_f(xv.z);
    yv.w = g * ((yv.w - m2) * rs2) + be + gelu_f(xv.w);
    ((float4*)y)[idx4] = yv;
}

extern "C" void kernel_launch(void* const* d_in, const int* in_sizes, int n_in,
                              void* d_out, int out_size, void* d_ws, size_t ws_size,
                              hipStream_t stream) {
    (void)in_sizes; (void)n_in; (void)out_size; (void)ws_size;
    const float* x       = (const float*)d_in[0];
    const float* t_in    = (const float*)d_in[1];
    const float* w1r     = (const float*)d_in[2];
    const float* w1i     = (const float*)d_in[3];
    const float* w2r     = (const float*)d_in[4];
    const float* w2i     = (const float*)d_in[5];
    const float* norm1_w = (const float*)d_in[6];
    const float* norm1_b = (const float*)d_in[7];
    const float* mlp_w1  = (const float*)d_in[8];
    const float* mlp_b1  = (const float*)d_in[9];
    const float* mlp_w2  = (const float*)d_in[10];
    const float* mlp_b2  = (const float*)d_in[11];
    const float* gamma_w = (const float*)d_in[12];
    const float* gamma_b = (const float*)d_in[13];
    const float* beta_w  = (const float*)d_in[14];
    const float* beta_b  = (const float*)d_in[15];
    float* out = (float*)d_out;
    float* ws  = (float*)d_ws;

    float* gn_acc   = ws;            // 32
    float* gamma_bc = ws + 32;       // 512
    float* beta_bc  = ws + 544;      // 512
    float* xw_re    = ws + 2048;     // 4194304
    float* xw_im    = xw_re + 4194304;
    float* xf_re    = xw_im + 4194304;  // 1048576
    float* xf_im    = xf_re + 1048576;
    float* yf_re    = xf_im + 1048576;
    float* yf_im    = yf_re + 1048576;
    // total ~50.4 MB of workspace

    k0_init<<<dim3(1), dim3(256), 0, stream>>>(t_in, gamma_w, gamma_b, beta_w, beta_b,
                                               gn_acc, gamma_bc, beta_bc);
    k1_dftw<<<dim3(4096), dim3(128), 0, stream>>>(x, xw_re, xw_im);
    k2_dfth<<<dim3(512), dim3(256), 0, stream>>>(xw_re, xw_im, xf_re, xf_im);
    k3_mix<<<dim3(1024), dim3(256), 0, stream>>>(xf_re, xf_im, w1r, w1i, w2r, w2i,
                                                 yf_re, yf_im);
    k4_idfth<<<dim3(2048), dim3(256), 0, stream>>>(yf_re, yf_im, xw_re, xw_im);
    k5_irfftw<<<dim3(1024), dim3(128), 0, stream>>>(xw_re, xw_im, out, gn_acc);
    k6_mlp<<<dim3(2048), dim3(256), 0, stream>>>(x, norm1_w, norm1_b, mlp_w1, mlp_b1,
                                                 mlp_w2, mlp_b2, out, gn_acc);
    k7_final<<<dim3(32768), dim3(256), 0, stream>>>(x, gamma_bc, beta_bc, gn_acc, out);
}

// Round 2
// 898.439 us; speedup vs baseline: 1.1825x; 1.1825x over previous
//
#include <hip/hip_runtime.h>
#include <math.h>

#define NB 8
#define NC 64
#define NH 256
#define NW 256
#define NHW 65536
#define NM 32
#define NPS 4194304   // C*H*W per sample
#define GN_EPS 1e-5f
#define OMEGA 0.0245436926061703f  // 2*pi/256

typedef short shortx8 __attribute__((ext_vector_type(8)));
typedef float floatx4 __attribute__((ext_vector_type(4)));

__device__ __forceinline__ float gelu_f(float v) {
    return 0.5f * v * (1.0f + erff(v * 0.7071067811865475f));
}

__device__ __forceinline__ unsigned short f2bf(float f) {
    unsigned u = __builtin_bit_cast(unsigned, f);
    u = (u + 0x7fffu + ((u >> 16) & 1u)) >> 16;
    return (unsigned short)u;
}

// ---------------- K0: zero GN accumulators, compute FiLM gamma/beta per (b,c)
__global__ void k0_init(const float* __restrict__ t_in,
                        const float* __restrict__ gamma_w, const float* __restrict__ gamma_b,
                        const float* __restrict__ beta_w, const float* __restrict__ beta_b,
                        float* __restrict__ gn_acc, float* __restrict__ gamma_bc,
                        float* __restrict__ beta_bc) {
    int t = threadIdx.x;
    if (t < 32) gn_acc[t] = 0.f;
    for (int idx = t; idx < NB * NC; idx += 256) {
        int b = idx >> 6, o = idx & 63;
        float g = gamma_b[o], be = beta_b[o];
        for (int c = 0; c < NC; ++c) {
            float tv = t_in[b * NC + c];
            g += gamma_w[o * NC + c] * tv;
            be += beta_w[o * NC + c] * tv;
        }
        gamma_bc[idx] = g;
        beta_bc[idx] = be;
    }
}

// ---------------- K1: real DFT along W, keep kx 0..31.  Xw[bc][h][kx]
__global__ __launch_bounds__(128) void k1_dftw(const float* __restrict__ x,
                                               float* __restrict__ xw_re,
                                               float* __restrict__ xw_im) {
    __shared__ float xs[32 * 257];
    int blk = blockIdx.x;        // 4096 = 512 bc * 8 hchunks
    int bc = blk >> 3;
    int h0 = (blk & 7) * 32;
    const float* src = x + (size_t)bc * NHW + (size_t)h0 * NW;
    for (int idx = threadIdx.x; idx < 2048; idx += 128) {
        float4 v = ((const float4*)src)[idx];
        int r = idx >> 6;
        int w = (idx & 63) * 4;
        float* d = &xs[r * 257 + w];
        d[0] = v.x; d[1] = v.y; d[2] = v.z; d[3] = v.w;
    }
    __syncthreads();
    int t = threadIdx.x;
    int row = t >> 2;       // 0..31
    int kgrp = t & 3;       // kx = kgrp*8 + j
    float cd[8], sd[8], cc[8], ss[8], ar[8], ai[8];
#pragma unroll
    for (int j = 0; j < 8; ++j) {
        int kx = kgrp * 8 + j;
        sincosf(OMEGA * (float)kx, &sd[j], &cd[j]);
        cc[j] = 1.f; ss[j] = 0.f; ar[j] = 0.f; ai[j] = 0.f;
    }
    const float* xrow = &xs[row * 257];
    for (int w = 0; w < 256; ++w) {
        float xv = xrow[w];
#pragma unroll
        for (int j = 0; j < 8; ++j) {
            ar[j] += xv * cc[j];        // e^{-i th}: re += x cos
            ai[j] -= xv * ss[j];        // im -= x sin
            float c2 = cc[j] * cd[j] - ss[j] * sd[j];
            ss[j] = ss[j] * cd[j] + cc[j] * sd[j];
            cc[j] = c2;
        }
    }
    size_t rowg = (size_t)bc * NH + h0 + row;
#pragma unroll
    for (int j = 0; j < 8; ++j) {
        int kx = kgrp * 8 + j;
        xw_re[rowg * NM + kx] = ar[j];
        xw_im[rowg * NM + kx] = ai[j];
    }
}

// ---------------- K2: complex DFT along H at kept rows.  Xf[bc][j64][kx]
__global__ __launch_bounds__(256) void k2_dfth(const float* __restrict__ xw_re,
                                               const float* __restrict__ xw_im,
                                               float* __restrict__ xf_re,
                                               float* __restrict__ xf_im) {
    __shared__ float xr_l[NH * NM];
    __shared__ float xi_l[NH * NM];
    int bc = blockIdx.x;
    size_t base = (size_t)bc * NH * NM;
    for (int idx = threadIdx.x; idx < NH * NM / 4; idx += 256) {
        ((float4*)xr_l)[idx] = ((const float4*)(xw_re + base))[idx];
        ((float4*)xi_l)[idx] = ((const float4*)(xw_im + base))[idx];
    }
    __syncthreads();
    int t = threadIdx.x;
    int kx = t & 31, jgrp = t >> 5;
    float cd[8], sd[8], cc[8], ss[8], ar[8], ai[8];
#pragma unroll
    for (int jj = 0; jj < 8; ++jj) {
        int j = jgrp * 8 + jj;
        int f = (j < 32) ? j : 192 + j;     // actual row frequency
        sincosf(OMEGA * (float)f, &sd[jj], &cd[jj]);
        cc[jj] = 1.f; ss[jj] = 0.f; ar[jj] = 0.f; ai[jj] = 0.f;
    }
    for (int h = 0; h < 256; ++h) {
        float xr = xr_l[h * NM + kx], xi = xi_l[h * NM + kx];
#pragma unroll
        for (int jj = 0; jj < 8; ++jj) {
            // (xr + i xi) * (c - i s)
            ar[jj] += xr * cc[jj] + xi * ss[jj];
            ai[jj] += xi * cc[jj] - xr * ss[jj];
            float c2 = cc[jj] * cd[jj] - ss[jj] * sd[jj];
            ss[jj] = ss[jj] * cd[jj] + cc[jj] * sd[jj];
            cc[jj] = c2;
        }
    }
    size_t ob = (size_t)bc * 2048;
#pragma unroll
    for (int jj = 0; jj < 8; ++jj) {
        int j = jgrp * 8 + jj;
        xf_re[ob + j * 32 + kx] = ar[jj];
        xf_im[ob + j * 32 + kx] = ai[jj];
    }
}

// ---------------- K3: per-mode complex channel mix.  Yf[b][o][ky][kx]
__global__ __launch_bounds__(256) void k3_mix(const float* __restrict__ xf_re,
                                              const float* __restrict__ xf_im,
                                              const float* __restrict__ w1r, const float* __restrict__ w1i,
                                              const float* __restrict__ w2r, const float* __restrict__ w2i,
                                              float* __restrict__ yf_re, float* __restrict__ yf_im) {
    __shared__ float xr_l[4 * 64 * 32];
    __shared__ float xi_l[4 * 64 * 32];
    int blk = blockIdx.x;          // ((ky*8 + oct)*2 + bh)
    int bh = blk & 1;
    int oct = (blk >> 1) & 7;
    int ky = blk >> 4;
    for (int idx = threadIdx.x; idx < 4 * 64 * 32; idx += 256) {
        int bb = idx >> 11;
        int i = (idx >> 5) & 63;
        int kx = idx & 31;
        size_t g = ((size_t)((bh * 4 + bb) * 64 + i) * 64 + ky) * 32 + kx;
        xr_l[idx] = xf_re[g];
        xi_l[idx] = xf_im[g];
    }
    __syncthreads();
    const float* wr = (ky < 32) ? w1r : w2r;
    const float* wi = (ky < 32) ? w1i : w2i;
    int kyl = ky & 31;
    int t = threadIdx.x;
    int kx = t & 31, oo = t >> 5;
    int o = oct * 8 + oo;
    float accr[4] = {0.f, 0.f, 0.f, 0.f};
    float acci[4] = {0.f, 0.f, 0.f, 0.f};
    for (int i = 0; i < 64; ++i) {
        size_t wbase = ((size_t)(i * 64 + o) * 32 + kyl) * 32 + kx;
        float wrv = wr[wbase];
        float wiv = wi[wbase];
#pragma unroll
        for (int bb = 0; bb < 4; ++bb) {
            float xr = xr_l[(bb * 64 + i) * 32 + kx];
            float xi = xi_l[(bb * 64 + i) * 32 + kx];
            accr[bb] += xr * wrv - xi * wiv;
            acci[bb] += xr * wiv + xi * wrv;
        }
    }
#pragma unroll
    for (int bb = 0; bb < 4; ++bb) {
        int b = bh * 4 + bb;
        size_t g = ((size_t)(b * 64 + o) * 64 + ky) * 32 + kx;
        yf_re[g] = accr[bb];
        yf_im[g] = acci[bb];
    }
}

// ---------------- K4: inverse DFT along H (only 64 nonzero rows).  Yh[bc][h][kx]
__global__ __launch_bounds__(256) void k4_idfth(const float* __restrict__ yf_re,
                                                const float* __restrict__ yf_im,
                                                float* __restrict__ yh_re,
                                                float* __restrict__ yh_im) {
    __shared__ float yr_l[2048];
    __shared__ float yi_l[2048];
    int blk = blockIdx.x;
    int bc = blk >> 2, hq = blk & 3;
    size_t base = (size_t)bc * 2048;
    for (int idx = threadIdx.x; idx < 512; idx += 256) {
        ((float4*)yr_l)[idx] = ((const float4*)(yf_re + base))[idx];
        ((float4*)yi_l)[idx] = ((const float4*)(yf_im + base))[idx];
    }
    __syncthreads();
    int t = threadIdx.x;
    int kx = t & 31, hgrp = t >> 5;
    int h0 = hq * 64 + hgrp * 8;
    float cdh[8], sdh[8], cc[8], ss[8], ar[8], ai[8];
#pragma unroll
    for (int hh = 0; hh < 8; ++hh) {
        sincosf(OMEGA * (float)(h0 + hh), &sdh[hh], &cdh[hh]);
        cc[hh] = 1.f; ss[hh] = 0.f; ar[hh] = 0.f; ai[hh] = 0.f;
    }
    for (int j = 0; j < 64; ++j) {
        if (j == 32) {
#pragma unroll
            for (int hh = 0; hh < 8; ++hh) ss[hh] = -ss[hh];
        }
        float yr = yr_l[j * 32 + kx], yi = yi_l[j * 32 + kx];
#pragma unroll
        for (int hh = 0; hh < 8; ++hh) {
            // (yr + i yi) * (c + i s)
            ar[hh] += yr * cc[hh] - yi * ss[hh];
            ai[hh] += yr * ss[hh] + yi * cc[hh];
            float c2 = cc[hh] * cdh[hh] - ss[hh] * sdh[hh];
            ss[hh] = ss[hh] * cdh[hh] + cc[hh] * sdh[hh];
            cc[hh] = c2;
        }
    }
    const float sc = 1.0f / 65536.0f;   // 1/(H*W) folded here
#pragma unroll
    for (int hh = 0; hh < 8; ++hh) {
        size_t g = ((size_t)bc * NH + h0 + hh) * NM + kx;
        yh_re[g] = ar[hh] * sc;
        yh_im[g] = ai[hh] * sc;
    }
}

// ---------------- K5: inverse real DFT along W + GN1 statistics.  y -> d_out
__global__ __launch_bounds__(128) void k5_irfftw(const float* __restrict__ yh_re,
                                                 const float* __restrict__ yh_im,
                                                 float* __restrict__ yout,
                                                 float* __restrict__ gn_acc) {
    __shared__ float zr_l[128 * 33];
    __shared__ float zi_l[128 * 33];
    __shared__ float rsum[2], rsq[2];
    int blk = blockIdx.x;
    int bc = blk >> 1, hhalf = blk & 1;
    size_t base = ((size_t)bc * NH + hhalf * 128) * NM;
    for (int idx = threadIdx.x; idx < 128 * 32; idx += 128) {
        int hl = idx >> 5, kx = idx & 31;
        zr_l[hl * 33 + kx] = yh_re[base + idx];
        zi_l[hl * 33 + kx] = yh_im[base + idx];
    }
    __syncthreads();
    int t = threadIdx.x;
    float zr[32], zi[32];
#pragma unroll
    for (int kx = 0; kx < 32; ++kx) {
        float m = (kx == 0) ? 1.f : 2.f;   // irfft doubling for kx>=1
        zr[kx] = zr_l[t * 33 + kx] * m;
        zi[kx] = zi_l[t * 33 + kx] * m;
    }
    int h = hhalf * 128 + t;
    float* orow = yout + (size_t)bc * NHW + (size_t)h * NW;
    float cw = 1.f, sw = 0.f;
    float cdw, sdw;
    sincosf(OMEGA, &sdw, &cdw);
    float sum = 0.f, sq = 0.f;
    for (int w4 = 0; w4 < 64; ++w4) {
        float res[4];
#pragma unroll
        for (int q = 0; q < 4; ++q) {
            float c = cw, s = sw;          // e^{+i*w*kx}, kx = 1
            float acc = zr[0];             // DC: Re only (pocketfft semantics)
#pragma unroll
            for (int kx = 1; kx < 32; ++kx) {
                acc += zr[kx] * c - zi[kx] * s;
                float c2 = c * cw - s * sw;
                s = s * cw + c * sw;
                c = c2;
            }
            res[q] = acc;
            sum += acc;
            sq += acc * acc;
            float c2 = cw * cdw - sw * sdw;  // advance w
            sw = sw * cdw + cw * sdw;
            cw = c2;
        }
        ((float4*)orow)[w4] = make_float4(res[0], res[1], res[2], res[3]);
    }
#pragma unroll
    for (int off = 32; off > 0; off >>= 1) {
        sum += __shfl_down(sum, off);
        sq += __shfl_down(sq, off);
    }
    int lane = t & 63, wv = t >> 6;
    if (lane == 0) { rsum[wv] = sum; rsq[wv] = sq; }
    __syncthreads();
    if (t == 0) {
        int b = bc >> 6;
        atomicAdd(&gn_acc[b * 4 + 0], rsum[0] + rsum[1]);
        atomicAdd(&gn_acc[b * 4 + 1], rsq[0] + rsq[1]);
    }
}

// ---------------- K6: GN1 + residual + gelu + MLP via bf16 MFMA + GN2 stats
// Block: 256 threads (4 waves), 128 pixels of one sample.
// LDS layout (byte offsets), phase-1 region aliased by fp32 out buffer:
//   vbuf   @0      128 x 72 bf16 = 18432   (A operand, gn+gelu'd input)
//   w1buf  @18432   32 x 72 bf16 = 4608    (B^T operand layer1)
//   hbuf   @23040  128 x 40 bf16 = 10240   (A operand layer2)
//   w2buf  @33280   64 x 40 bf16 = 5120    (B^T operand layer2)
//   outbuf @0       64 x 132 f32 = 33792   (aliases vbuf/w1buf/hbuf; safe: sync)
//   params @38400  nw,nb(64) b1(32) b2(64) f32 = 896
//   red    @39296  8 f32
__global__ __launch_bounds__(256, 4) void k6_mlp(const float* __restrict__ x,
                                                 const float* __restrict__ norm1_w,
                                                 const float* __restrict__ norm1_b,
                                                 const float* __restrict__ mlp_w1,
                                                 const float* __restrict__ mlp_b1,
                                                 const float* __restrict__ mlp_w2,
                                                 const float* __restrict__ mlp_b2,
                                                 float* __restrict__ y,
                                                 float* __restrict__ gn_acc) {
    __shared__ __align__(16) unsigned char smem[39328];
    unsigned short* vbuf  = (unsigned short*)smem;
    unsigned short* w1buf = (unsigned short*)(smem + 18432);
    unsigned short* hbuf  = (unsigned short*)(smem + 23040);
    unsigned short* w2buf = (unsigned short*)(smem + 33280);
    float* outbuf = (float*)smem;                 // alias (phase 2)
    float* nwl = (float*)(smem + 38400);
    float* nbl = nwl + 64;
    float* b1l = nbl + 64;
    float* b2l = b1l + 32;
    float* red = b2l + 64;

    int t = threadIdx.x;
    int blk = blockIdx.x;
    int b = blk >> 9;                  // 512 blocks per sample
    int pixbase = (blk & 511) * 128;
    size_t bbase = (size_t)b * NC * NHW + pixbase;

    // --- load weights (fp32 -> bf16) + params
    for (int idx = t; idx < 2048; idx += 256) {
        w1buf[(idx >> 6) * 72 + (idx & 63)] = f2bf(mlp_w1[idx]);
        w2buf[(idx >> 5) * 40 + (idx & 31)] = f2bf(mlp_w2[idx]);
    }
    if (t < 64) { nwl[t] = norm1_w[t]; nbl[t] = norm1_b[t]; b2l[t] = mlp_b2[t]; }
    if (t >= 64 && t < 96) b1l[t - 64] = mlp_b1[t - 64];

    // --- stage 1: v = gelu(gn1(y)*nw+nb + x), bf16 into vbuf[pix][c]
    const float invN = 1.0f / (float)NPS;
    float m1 = gn_acc[b * 4 + 0] * invN;
    float var1 = gn_acc[b * 4 + 1] * invN - m1 * m1;
    float rs1 = rsqrtf(var1 + GN_EPS);
    {
        int p = t & 127;
        int c0 = (t >> 7) * 32;
        size_t base = bbase + (size_t)c0 * NHW + p;
#pragma unroll 8
        for (int ci = 0; ci < 32; ++ci) {
            float yv = y[base + (size_t)ci * NHW];
            float xv = x[base + (size_t)ci * NHW];
            int c = c0 + ci;
            float g = (yv - m1) * rs1 * nwl[c] + nbl[c] + xv;
            vbuf[p * 72 + c] = f2bf(gelu_f(g));
        }
    }
    __syncthreads();

    int lane = t & 63, wv = t >> 6;
    int lm = lane & 15, lg = lane >> 4;

    // --- layer 1 MFMA: h[128x32] = v[128x64] @ w1^T, + b1, gelu -> hbuf bf16
    floatx4 acc1[2][2] = {};
#pragma unroll
    for (int ks = 0; ks < 2; ++ks) {
        shortx8 a[2], bf[2];
#pragma unroll
        for (int mt = 0; mt < 2; ++mt)
            a[mt] = *(const shortx8*)&vbuf[(wv * 32 + mt * 16 + lm) * 72 + lg * 8 + ks * 32];
#pragma unroll
        for (int nt = 0; nt < 2; ++nt)
            bf[nt] = *(const shortx8*)&w1buf[(nt * 16 + lm) * 72 + lg * 8 + ks * 32];
#pragma unroll
        for (int mt = 0; mt < 2; ++mt)
#pragma unroll
            for (int nt = 0; nt < 2; ++nt)
                acc1[mt][nt] = __builtin_amdgcn_mfma_f32_16x16x32_bf16(a[mt], bf[nt], acc1[mt][nt], 0, 0, 0);
    }
#pragma unroll
    for (int mt = 0; mt < 2; ++mt)
#pragma unroll
        for (int nt = 0; nt < 2; ++nt) {
            float b1v = b1l[nt * 16 + lm];
#pragma unroll
            for (int r = 0; r < 4; ++r) {
                float hv = gelu_f(acc1[mt][nt][r] + b1v);
                hbuf[(wv * 32 + mt * 16 + lg * 4 + r) * 40 + nt * 16 + lm] = f2bf(hv);
            }
        }
    __syncthreads();

    // --- layer 2 MFMA: out[128x64] = h[128x32] @ w2^T
    floatx4 acc2[2][4] = {};
    {
        shortx8 a2[2], b2f[4];
#pragma unroll
        for (int mt = 0; mt < 2; ++mt)
            a2[mt] = *(const shortx8*)&hbuf[(wv * 32 + mt * 16 + lm) * 40 + lg * 8];
#pragma unroll
        for (int nt = 0; nt < 4; ++nt)
            b2f[nt] = *(const shortx8*)&w2buf[(nt * 16 + lm) * 40 + lg * 8];
#pragma unroll
        for (int mt = 0; mt < 2; ++mt)
#pragma unroll
            for (int nt = 0; nt < 4; ++nt)
                acc2[mt][nt] = __builtin_amdgcn_mfma_f32_16x16x32_bf16(a2[mt], b2f[nt], acc2[mt][nt], 0, 0, 0);
    }
    __syncthreads();   // all hbuf/w2buf reads done; outbuf may now clobber

    // --- write C-layout to fp32 outbuf[ch][pix] (+bias)
#pragma unroll
    for (int mt = 0; mt < 2; ++mt)
#pragma unroll
        for (int nt = 0; nt < 4; ++nt) {
            int ch = nt * 16 + lm;
            float b2v = b2l[ch];
#pragma unroll
            for (int r = 0; r < 4; ++r)
                outbuf[ch * 132 + wv * 32 + mt * 16 + lg * 4 + r] = acc2[mt][nt][r] + b2v;
        }
    __syncthreads();

    // --- coalesced global store + GN2 stats
    float sum = 0.f, sq = 0.f;
#pragma unroll
    for (int it = 0; it < 8; ++it) {
        int flat = it * 256 + t;
        int c = flat >> 5;
        int p4 = (flat & 31) * 4;
        float4 v = *(const float4*)&outbuf[c * 132 + p4];
        *(float4*)&y[bbase + (size_t)c * NHW + p4] = v;
        sum += v.x + v.y + v.z + v.w;
        sq += v.x * v.x + v.y * v.y + v.z * v.z + v.w * v.w;
    }
#pragma unroll
    for (int off = 32; off > 0; off >>= 1) {
        sum += __shfl_down(sum, off);
        sq += __shfl_down(sq, off);
    }
    if (lane == 0) { red[wv] = sum; red[4 + wv] = sq; }
    __syncthreads();
    if (t == 0) {
        atomicAdd(&gn_acc[b * 4 + 2], red[0] + red[1] + red[2] + red[3]);
        atomicAdd(&gn_acc[b * 4 + 3], red[4] + red[5] + red[6] + red[7]);
    }
}

// ---------------- K7: GN2 + FiLM + gelu(x) skip, elementwise, in-place
__global__ __launch_bounds__(256) void k7_final(const float* __restrict__ x,
                                                const float* __restrict__ gamma_bc,
                                                const float* __restrict__ beta_bc,
                                                const float* __restrict__ gn_acc,
                                                float* __restrict__ y) {
    size_t idx4 = (size_t)blockIdx.x * 256 + threadIdx.x;
    size_t base = idx4 * 4;
    int b = (int)(base >> 22);
    int c = (int)((base >> 16) & 63);
    const float invN = 1.0f / (float)NPS;
    float m2 = gn_acc[b * 4 + 2] * invN;
    float var2 = gn_acc[b * 4 + 3] * invN - m2 * m2;
    float rs2 = rsqrtf(var2 + GN_EPS);
    float g = gamma_bc[b * 64 + c];
    float be = beta_bc[b * 64 + c];
    float4 yv = ((float4*)y)[idx4];
    float4 xv = ((const float4*)x)[idx4];
    yv.x = g * ((yv.x - m2) * rs2) + be + gelu_f(xv.x);
    yv.y = g * ((yv.y - m2) * rs2) + be + gelu_f(xv.y);
    yv.z = g * ((yv.z - m2) * rs2) + be + gelu_f(xv.z);
    yv.w = g * ((yv.w - m2) * rs2) + be + gelu_f(xv.w);
    ((float4*)y)[idx4] = yv;
}

extern "C" void kernel_launch(void* const* d_in, const int* in_sizes, int n_in,
                              void* d_out, int out_size, void* d_ws, size_t ws_size,
                              hipStream_t stream) {
    (void)in_sizes; (void)n_in; (void)out_size; (void)ws_size;
    const float* x       = (const float*)d_in[0];
    const float* t_in    = (const float*)d_in[1];
    const float* w1r     = (const float*)d_in[2];
    const float* w1i     = (const float*)d_in[3];
    const float* w2r     = (const float*)d_in[4];
    const float* w2i     = (const float*)d_in[5];
    const float* norm1_w = (const float*)d_in[6];
    const float* norm1_b = (const float*)d_in[7];
    const float* mlp_w1  = (const float*)d_in[8];
    const float* mlp_b1  = (const float*)d_in[9];
    const float* mlp_w2  = (const float*)d_in[10];
    const float* mlp_b2  = (const float*)d_in[11];
    const float* gamma_w = (const float*)d_in[12];
    const float* gamma_b = (const float*)d_in[13];
    const float* beta_w  = (const float*)d_in[14];
    const float* beta_b  = (const float*)d_in[15];
    float* out = (float*)d_out;
    float* ws  = (float*)d_ws;

    float* gn_acc   = ws;            // 32
    float* gamma_bc = ws + 32;       // 512
    float* beta_bc  = ws + 544;      // 512
    float* xw_re    = ws + 2048;     // 4194304
    float* xw_im    = xw_re + 4194304;
    float* xf_re    = xw_im + 4194304;  // 1048576
    float* xf_im    = xf_re + 1048576;
    float* yf_re    = xf_im + 1048576;
    float* yf_im    = yf_re + 1048576;

    k0_init<<<dim3(1), dim3(256), 0, stream>>>(t_in, gamma_w, gamma_b, beta_w, beta_b,
                                               gn_acc, gamma_bc, beta_bc);
    k1_dftw<<<dim3(4096), dim3(128), 0, stream>>>(x, xw_re, xw_im);
    k2_dfth<<<dim3(512), dim3(256), 0, stream>>>(xw_re, xw_im, xf_re, xf_im);
    k3_mix<<<dim3(1024), dim3(256), 0, stream>>>(xf_re, xf_im, w1r, w1i, w2r, w2i,
                                                 yf_re, yf_im);
    k4_idfth<<<dim3(2048), dim3(256), 0, stream>>>(yf_re, yf_im, xw_re, xw_im);
    k5_irfftw<<<dim3(1024), dim3(128), 0, stream>>>(xw_re, xw_im, out, gn_acc);
    k6_mlp<<<dim3(4096), dim3(256), 0, stream>>>(x, norm1_w, norm1_b, mlp_w1, mlp_b1,
                                                 mlp_w2, mlp_b2, out, gn_acc);
    k7_final<<<dim3(32768), dim3(256), 0, stream>>>(x, gamma_bc, beta_bc, gn_acc, out);
}